// Round 7
// baseline (68.363 us; speedup 1.0000x reference)
//
#include <hip/hip_runtime.h>

#define N_CELLS 100000
#define IN_CH 64
#define N_EDGES 1280000

// ---- bf16 helpers (bit-level, RNE) ----
__device__ __forceinline__ unsigned short f32_to_bf16(float f) {
    unsigned u = __float_as_uint(f);
    u += 0x7FFFu + ((u >> 16) & 1u);   // round to nearest even
    return (unsigned short)(u >> 16);
}
__device__ __forceinline__ float bf16_lo(unsigned h) {   // low ushort -> f32
    return __uint_as_float(h << 16);
}
__device__ __forceinline__ float bf16_hi(unsigned h) {   // high ushort -> f32
    return __uint_as_float(h & 0xFFFF0000u);
}

#define SCORE_BLOCKS ((N_CELLS * 16 + 255) / 256)
#define ROWSTART_BLOCKS ((N_EDGES + 255) / 256)

// Fused kernel 1: blocks [0, SCORE_BLOCKS) compute per-cell scores + bf16 x copy
// in split layout xb[2][N][32]; blocks after that build CSR row offsets.
__global__ void __launch_bounds__(256) prep_kernel(
    const float* __restrict__ x, const float* __restrict__ w,
    const int* __restrict__ tgt,
    float* __restrict__ s_src, float* __restrict__ s_tgt,
    unsigned short* __restrict__ xb, int* __restrict__ row_start,
    int n_cells, int n_edges) {
    if (blockIdx.x < SCORE_BLOCKS) {
        int gid  = blockIdx.x * 256 + threadIdx.x;
        int wave = gid >> 6;
        int lane = threadIdx.x & 63;
        int grp  = lane >> 4;
        int sub  = lane & 15;
        int cell = wave * 4 + grp;

        float4 xv = make_float4(0.f, 0.f, 0.f, 0.f);
        if (cell < n_cells)
            xv = *(const float4*)&x[(((unsigned)cell << 6) | ((unsigned)sub << 2))];
        if (xb && cell < n_cells) {
            ushort4 hb;
            hb.x = f32_to_bf16(xv.x); hb.y = f32_to_bf16(xv.y);
            hb.z = f32_to_bf16(xv.z); hb.w = f32_to_bf16(xv.w);
            // split layout: half = sub>>3 (channels 0-31 vs 32-63),
            // within-half ushort offset = cell*32 + (sub&7)*4
            unsigned idx = (unsigned)(sub >> 3) * ((unsigned)n_cells << 5)
                         + ((unsigned)cell << 5) + (((unsigned)sub & 7) << 2);
            *(ushort4*)&xb[idx] = hb;
        }
        const float4* w4 = (const float4*)w;
        float4 wa = w4[sub];
        float4 wb = w4[16 + sub];
        float a = xv.x * wa.x + xv.y * wa.y + xv.z * wa.z + xv.w * wa.w;
        float b = xv.x * wb.x + xv.y * wb.y + xv.z * wb.z + xv.w * wb.w;
#pragma unroll
        for (int off = 8; off; off >>= 1) {
            a += __shfl_xor(a, off, 64);
            b += __shfl_xor(b, off, 64);
        }
        if (sub == 0 && cell < n_cells) {
            s_src[cell] = a;
            s_tgt[cell] = b;
        }
    } else {
        int e = (blockIdx.x - SCORE_BLOCKS) * 256 + threadIdx.x;
        if (e >= n_edges) return;
        int lane = threadIdx.x & 63;
        int t = tgt[e];
        int prev = __shfl_up(t, 1, 64);
        if (lane == 0) prev = (e == 0) ? -1 : tgt[e - 1];
        for (int c = prev + 1; c <= t; ++c) row_start[c] = e;
        if (e == n_edges - 1) {
            for (int c = t + 1; c <= n_cells; ++c) row_start[c] = n_edges;
        }
    }
}

// Kernel 2: channel-split gather. 2*n_cells 16-lane groups; group g < n_cells does
// cell g channels [0,32), group g >= n_cells does cell g-n_cells channels [32,64).
// Each lane gathers one dword (2 bf16 channels) per edge. Blocks dispatch roughly
// in order, so the two 6.4 MB table halves are hot at disjoint times -> higher L2
// hit rate. v is recomputed per half (no cross-half ordering dependence).
__global__ void __launch_bounds__(256) agg_kernel_split(
    const unsigned short* __restrict__ xb, const int* __restrict__ src,
    const float* __restrict__ nbhd,
    const float* __restrict__ s_src, const float* __restrict__ s_tgt,
    const int* __restrict__ row_start,
    float* __restrict__ out, int n_cells) {
    int gid  = blockIdx.x * blockDim.x + threadIdx.x;
    int lane = threadIdx.x & 63;
    int grp  = lane >> 4;
    int sub  = lane & 15;
    int g    = (gid >> 6) * 4 + grp;
    int half = (g >= n_cells) ? 1 : 0;
    int cell = g - half * n_cells;
    if (cell >= n_cells) return;
    int gbase = grp << 4;
    const unsigned short* xh = xb + (size_t)half * ((size_t)n_cells << 5);
    unsigned choff = (unsigned)sub << 1;            // ushort offset within 32-ch half

    int lo  = row_start[cell];
    int hi  = row_start[cell + 1];
    float sti = s_tgt[cell];

    float2 acc = make_float2(0.f, 0.f);
    for (int base = lo; base < hi; base += 16) {
        int cnt = hi - base;
        if (cnt > 16) cnt = 16;
        int   j = 0;
        float v = 0.f;
        if (sub < cnt) {
            j = src[base + sub];
            float a = s_src[j] + sti;
            v = nbhd[base + sub] * (a > 0.f ? a : expm1f(a));
        }
        int t = 0;
        for (; t + 4 <= cnt; t += 4) {
            int   j0 = __shfl(j, gbase + t,     64);
            int   j1 = __shfl(j, gbase + t + 1, 64);
            int   j2 = __shfl(j, gbase + t + 2, 64);
            int   j3 = __shfl(j, gbase + t + 3, 64);
            float v0 = __shfl(v, gbase + t,     64);
            float v1 = __shfl(v, gbase + t + 1, 64);
            float v2 = __shfl(v, gbase + t + 2, 64);
            float v3 = __shfl(v, gbase + t + 3, 64);
            unsigned h0 = *(const unsigned*)&xh[(((unsigned)j0 << 5) | choff)];
            unsigned h1 = *(const unsigned*)&xh[(((unsigned)j1 << 5) | choff)];
            unsigned h2 = *(const unsigned*)&xh[(((unsigned)j2 << 5) | choff)];
            unsigned h3 = *(const unsigned*)&xh[(((unsigned)j3 << 5) | choff)];
            acc.x = fmaf(v0, bf16_lo(h0), acc.x);
            acc.y = fmaf(v0, bf16_hi(h0), acc.y);
            acc.x = fmaf(v1, bf16_lo(h1), acc.x);
            acc.y = fmaf(v1, bf16_hi(h1), acc.y);
            acc.x = fmaf(v2, bf16_lo(h2), acc.x);
            acc.y = fmaf(v2, bf16_hi(h2), acc.y);
            acc.x = fmaf(v3, bf16_lo(h3), acc.x);
            acc.y = fmaf(v3, bf16_hi(h3), acc.y);
        }
        for (; t < cnt; ++t) {
            int   jt = __shfl(j, gbase + t, 64);
            float vt = __shfl(v, gbase + t, 64);
            unsigned ht = *(const unsigned*)&xh[(((unsigned)jt << 5) | choff)];
            acc.x = fmaf(vt, bf16_lo(ht), acc.x);
            acc.y = fmaf(vt, bf16_hi(ht), acc.y);
        }
    }
    // out channel index = half*32 + sub*2
    *(float2*)&out[(((unsigned)cell << 6) | ((unsigned)half << 5) | choff)] = acc;
}

// Fallback f32-gather version (used only if workspace is too small for xb).
__global__ void __launch_bounds__(256) agg_kernel_f32(
    const float* __restrict__ x, const int* __restrict__ src,
    const float* __restrict__ nbhd,
    const float* __restrict__ s_src, const float* __restrict__ s_tgt,
    const int* __restrict__ row_start,
    float* __restrict__ out, int n_cells) {
    int gid  = blockIdx.x * blockDim.x + threadIdx.x;
    int lane = threadIdx.x & 63;
    int grp  = lane >> 4;
    int sub  = lane & 15;
    int cell = (gid >> 6) * 4 + grp;
    unsigned suboff = (unsigned)sub << 2;
    int gbase = grp << 4;

    int lo = 0, hi = 0;
    float sti = 0.f;
    if (cell < n_cells) {
        lo  = row_start[cell];
        hi  = row_start[cell + 1];
        sti = s_tgt[cell];
    }
    float4 acc = make_float4(0.f, 0.f, 0.f, 0.f);
    for (int base = lo; base < hi; base += 16) {
        int cnt = hi - base;
        if (cnt > 16) cnt = 16;
        int   j = 0;
        float v = 0.f;
        if (sub < cnt) {
            j = src[base + sub];
            float a = s_src[j] + sti;
            v = nbhd[base + sub] * (a > 0.f ? a : expm1f(a));
        }
        for (int t = 0; t < cnt; ++t) {
            int   jt = __shfl(j, gbase + t, 64);
            float vt = __shfl(v, gbase + t, 64);
            float4 xt = *(const float4*)&x[(((unsigned)jt << 6) | suboff)];
            acc.x = fmaf(vt, xt.x, acc.x); acc.y = fmaf(vt, xt.y, acc.y);
            acc.z = fmaf(vt, xt.z, acc.z); acc.w = fmaf(vt, xt.w, acc.w);
        }
    }
    if (cell < n_cells)
        *(float4*)&out[(((unsigned)cell << 6) | suboff)] = acc;
}

extern "C" void kernel_launch(void* const* d_in, const int* in_sizes, int n_in,
                              void* d_out, int out_size, void* d_ws, size_t ws_size,
                              hipStream_t stream) {
    const float* x    = (const float*)d_in[0];   // [N_CELLS, 64]
    const float* w    = (const float*)d_in[1];   // [128]
    const float* nbhd = (const float*)d_in[2];   // [N_EDGES]
    const int*   tgt  = (const int*)d_in[3];     // [N_EDGES] sorted
    const int*   src  = (const int*)d_in[4];     // [N_EDGES]
    float*       out  = (float*)d_out;           // [N_CELLS, 64]

    // workspace layout
    float* s_src     = (float*)d_ws;                       // N_CELLS f32
    float* s_tgt     = s_src + N_CELLS;                    // N_CELLS f32
    int*   row_start = (int*)(s_tgt + N_CELLS);            // N_CELLS+1 i32
    unsigned short* xb = (unsigned short*)(row_start + N_CELLS + 1);  // 2*N_CELLS*32 bf16
    size_t need_bf16 = (size_t)(2 * N_CELLS + N_CELLS + 1) * 4 + (size_t)N_CELLS * IN_CH * 2;
    bool use_bf16 = ws_size >= need_bf16;

    {
        int blocks = SCORE_BLOCKS + ROWSTART_BLOCKS;
        prep_kernel<<<blocks, 256, 0, stream>>>(x, w, tgt, s_src, s_tgt,
                                                use_bf16 ? xb : (unsigned short*)nullptr,
                                                row_start, N_CELLS, N_EDGES);
    }
    if (use_bf16) {
        int threads = 256;
        int blocks  = (2 * N_CELLS * 16 + threads - 1) / threads;   // 12500
        agg_kernel_split<<<blocks, threads, 0, stream>>>(xb, src, nbhd, s_src, s_tgt,
                                                         row_start, out, N_CELLS);
    } else {
        int threads = 256;
        int blocks  = (N_CELLS * 16 + threads - 1) / threads;
        agg_kernel_f32<<<blocks, threads, 0, stream>>>(x, src, nbhd, s_src, s_tgt,
                                                       row_start, out, N_CELLS);
    }
}